// Round 13
// baseline (124.290 us; speedup 1.0000x reference)
//
#include <hip/hip_runtime.h>

// Linear attention (chunked cumulative state), B=4 H=8 N=4096 D=E=64 CHUNK=128.
// SINGLE fused kernel: 512 blocks x 2 chunk-slots. Each block stages K/V once
// (K row-major swizzled via column loads that also yield p1's A-frags in regs;
// V subtiled), computes its chunk state (K^T V MFMA) + fp32 k-colsums, signals
// a per-bh counter (release fence + atomicAdd), spins until all 32 chunks of
// its bh are written (acquire fence), accumulates the exclusive chunk prefix
// (fp32, r5 path -> st_lds), then computes the output from the SAME LDS tiles
// (swapped QK^T, in-register S via shfl, in-fragment denominator).
// All 512 blocks co-resident (72KB LDS -> 2/CU) => spin is deadlock-free.

#define CHUNKSZ 128
#define DD 64
#define EE 64
#define NC 32          // N / CHUNK
#define NBH 32         // B*H
#define NSEQ 4096
#define EPSV 1e-6f
#define OUT0 (NBH * NSEQ * EE)           // start of Z output
#define KV_ELEMS (NBH * NC * DD * EE)    // ushort count

typedef short bf16x8 __attribute__((ext_vector_type(8)));
typedef short bf16x4 __attribute__((ext_vector_type(4)));
typedef float f32x4  __attribute__((ext_vector_type(4)));

__device__ __forceinline__ unsigned short f2bf(float f) {
    union { float f; unsigned u; } x; x.f = f;
    unsigned u = x.u + 0x7FFFu + ((x.u >> 16) & 1u);   // RNE
    return (unsigned short)(u >> 16);
}
__device__ __forceinline__ float bf2f(unsigned short s) {
    union { unsigned u; float f; } x; x.u = ((unsigned)s) << 16;
    return x.f;
}

__global__ __launch_bounds__(256, 2) void la_fused(
    const float* __restrict__ q, const float* __restrict__ k,
    const float* __restrict__ v, unsigned short* __restrict__ kvT,
    float* __restrict__ ks, int* __restrict__ cnt, float* __restrict__ out)
{
    const int b   = blockIdx.x;        // 0..511
    const int c   = b & 31;            // chunk index (same for both slots)
    const int bh0 = b >> 5;            // slot0 bh; slot1 bh = bh0 + 16

    __shared__ alignas(16) unsigned short k_lds[2][CHUNKSZ * DD];  // row-major swz
    __shared__ alignas(16) unsigned short v_lds[2][CHUNKSZ * EE];  // subtiled
    __shared__ alignas(16) unsigned short st_lds[DD * EE];         // state^T swz
    __shared__ float zi_lds[DD];

    const int t  = threadIdx.x;
    const int w  = t >> 6;
    const int l  = t & 63;
    const int lg = l >> 4;
    const int lm = l & 15;

    // ================= phase-1 part: both slots =================
#pragma unroll
    for (int s = 0; s < 2; ++s) {
        const int bh = bh0 + 16 * s;
        const size_t rowbase = (size_t)bh * NSEQ + (size_t)c * CHUNKSZ;
        char* kb = (char*)k_lds[s];
        char* vb = (char*)v_lds[s];

        // K column loads: d = 16w+lm, m-groups {lg, lg+4, lg+8, lg+12}.
        // Yields p1 A-frags directly (akf[kk] = group lg+4kk) and the row-major
        // swizzled k_lds (scalar 2B writes, ~4-way, staging-phase only).
        bf16x8 akf[4];
        {
            const int d = 16 * w + lm;
            const float* kp = k + rowbase * DD + d;
            float ksum = 0.f;
#pragma unroll
            for (int p = 0; p < 4; ++p) {
                const int mg = lg + 4 * p;
                float kf[8];
#pragma unroll
                for (int j = 0; j < 8; ++j) kf[j] = kp[(size_t)(mg * 8 + j) * DD];
                bf16x8 u;
#pragma unroll
                for (int j = 0; j < 8; ++j) { ksum += kf[j]; u[j] = (short)f2bf(kf[j]); }
                akf[p] = u;
#pragma unroll
                for (int j = 0; j < 8; ++j) {
                    int m = mg * 8 + j;
                    *(unsigned short*)(kb + m * 128 + ((2 * d) ^ ((m & 7) << 4))) =
                        (unsigned short)u[j];
                }
            }
            ksum += __shfl_xor(ksum, 16);
            ksum += __shfl_xor(ksum, 32);
            if (lg == 0) ks[(size_t)(bh * NC + c) * DD + d] = ksum;
        }
        // V column-pack -> subtiled v_lds (16B vector writes)
        {
            const float* vp = v + rowbase * EE + l;
#pragma unroll
            for (int p = 0; p < 4; ++p) {
                const int mg = w + 4 * p;
                float vf[8];
#pragma unroll
                for (int j = 0; j < 8; ++j) vf[j] = vp[(size_t)(mg * 8 + j) * EE];
                bf16x8 u;
#pragma unroll
                for (int j = 0; j < 8; ++j) u[j] = (short)f2bf(vf[j]);
                *(bf16x8*)(vb + mg * 1024 + l * 16) = u;
            }
        }
        __syncthreads();

        // K^T V MFMA: wave w owns d-tile w
        f32x4 acc[4] = {};
#pragma unroll
        for (int kk = 0; kk < 4; ++kk) {
#pragma unroll
            for (int ei = 0; ei < 4; ++ei) {
                bf16x8 bV = *(bf16x8*)(vb + (lg + 4 * kk) * 1024 + (16 * ei + lm) * 16);
                acc[ei] = __builtin_amdgcn_mfma_f32_16x16x32_bf16(akf[kk], bV, acc[ei], 0, 0, 0);
            }
        }
        // store state tile transposed [e][d] bf16
        unsigned short* kvout = kvT + (size_t)(bh * NC + c) * DD * EE;
#pragma unroll
        for (int ei = 0; ei < 4; ++ei) {
            bf16x4 u;
            u[0] = (short)f2bf(acc[ei][0]); u[1] = (short)f2bf(acc[ei][1]);
            u[2] = (short)f2bf(acc[ei][2]); u[3] = (short)f2bf(acc[ei][3]);
            *(bf16x4*)(kvout + (16 * ei + lm) * DD + 16 * w + 4 * lg) = u;
        }
        __syncthreads();                       // drain all waves' stores (vmcnt0)
        if (t == 0) {
            __builtin_amdgcn_fence(__ATOMIC_RELEASE, "agent");
            atomicAdd(&cnt[bh], 1);
        }
    }

    // ================= phase-3 part: both slots =================
    const int src1 = 32 * (lg & 1) + lm;
    const int src2 = src1 + 16;
    const int par  = lg >> 1;

#pragma unroll
    for (int s = 0; s < 2; ++s) {
        const int bh = bh0 + 16 * s;
        const size_t rowbase = (size_t)bh * NSEQ + (size_t)c * CHUNKSZ;
        char* kb  = (char*)k_lds[s];
        char* vb  = (char*)v_lds[s];
        char* stb = (char*)st_lds;

        // wait until all 32 chunks of this bh are written
        if (t == 0) {
            while (__hip_atomic_load(cnt + bh, __ATOMIC_RELAXED,
                                     __HIP_MEMORY_SCOPE_AGENT) < NC)
                __builtin_amdgcn_s_sleep(8);
        }
        __syncthreads();                       // also guards st/zi reuse from slot0
        __builtin_amdgcn_fence(__ATOMIC_ACQUIRE, "agent");

        // Z exclusive prefix (fp32) + Z tail
        if (t < DD) {
            const float* kp = ks + (size_t)bh * NC * DD + t;
            float z = 0.f;
            for (int j = 0; j < c; ++j) z += kp[(size_t)j * DD];
            zi_lds[t] = z;
            if (c == NC - 1)
                out[OUT0 + (size_t)bh * DD + t] = z + kp[(size_t)(NC - 1) * DD];
        }
        // state exclusive prefix: thread owns 16 elems (e = t>>2, d0 = (t&3)*16)
        float stacc[16];
#pragma unroll
        for (int u = 0; u < 16; ++u) stacc[u] = 0.f;
        {
            const unsigned short* tp = kvT + (size_t)bh * NC * DD * EE + (size_t)t * 16;
            int j = 0;
            for (; j + 4 <= c; j += 4) {
                bf16x8 a0 = *(const bf16x8*)(tp + (size_t)(j + 0) * DD * EE);
                bf16x8 b0 = *(const bf16x8*)(tp + (size_t)(j + 0) * DD * EE + 8);
                bf16x8 a1 = *(const bf16x8*)(tp + (size_t)(j + 1) * DD * EE);
                bf16x8 b1 = *(const bf16x8*)(tp + (size_t)(j + 1) * DD * EE + 8);
                bf16x8 a2 = *(const bf16x8*)(tp + (size_t)(j + 2) * DD * EE);
                bf16x8 b2 = *(const bf16x8*)(tp + (size_t)(j + 2) * DD * EE + 8);
                bf16x8 a3 = *(const bf16x8*)(tp + (size_t)(j + 3) * DD * EE);
                bf16x8 b3 = *(const bf16x8*)(tp + (size_t)(j + 3) * DD * EE + 8);
#pragma unroll
                for (int u = 0; u < 8; ++u) {
                    stacc[u]     += bf2f((unsigned short)a0[u]) + bf2f((unsigned short)a1[u])
                                  + bf2f((unsigned short)a2[u]) + bf2f((unsigned short)a3[u]);
                    stacc[8 + u] += bf2f((unsigned short)b0[u]) + bf2f((unsigned short)b1[u])
                                  + bf2f((unsigned short)b2[u]) + bf2f((unsigned short)b3[u]);
                }
            }
            for (; j < c; ++j) {
                bf16x8 a = *(const bf16x8*)(tp + (size_t)j * DD * EE);
                bf16x8 bb = *(const bf16x8*)(tp + (size_t)j * DD * EE + 8);
#pragma unroll
                for (int u = 0; u < 8; ++u) {
                    stacc[u]     += bf2f((unsigned short)a[u]);
                    stacc[8 + u] += bf2f((unsigned short)bb[u]);
                }
            }
        }
        // write exclusive prefix -> swizzled st_lds (bf16)
        {
            const int e = t >> 2, d0 = (t & 3) * 16;
            bf16x8 u0, u1;
#pragma unroll
            for (int u = 0; u < 8; ++u) {
                u0[u] = (short)f2bf(stacc[u]);
                u1[u] = (short)f2bf(stacc[8 + u]);
            }
            *(bf16x8*)(stb + e * 128 + ((2 * d0) ^ ((e & 7) << 4)))       = u0;
            *(bf16x8*)(stb + e * 128 + ((2 * (d0 + 8)) ^ ((e & 7) << 4))) = u1;
        }
        // S tail (inclusive, fp32, [d][e]) from the c==31 block
        if (c == NC - 1) {
            const unsigned short* own = kvT + ((size_t)bh * NC + NC - 1) * DD * EE + (size_t)t * 16;
            bf16x8 a = *(const bf16x8*)own;
            bf16x8 bb = *(const bf16x8*)(own + 8);
            const int e = t >> 2, d0 = (t & 3) * 16;
            float* Sout = out + OUT0 + NBH * DD + (size_t)bh * DD * EE;
#pragma unroll
            for (int u = 0; u < 8; ++u)
                Sout[(size_t)(d0 + u) * EE + e] = stacc[u] + bf2f((unsigned short)a[u]);
#pragma unroll
            for (int u = 0; u < 8; ++u)
                Sout[(size_t)(d0 + 8 + u) * EE + e] = stacc[8 + u] + bf2f((unsigned short)bb[u]);
        }
        __syncthreads();

        // state B-frags from st_lds
        bf16x8 b_st[4][2];
#pragma unroll
        for (int ei = 0; ei < 4; ++ei)
#pragma unroll
            for (int kk = 0; kk < 2; ++kk) {
                int e = 16 * ei + lm;
                b_st[ei][kk] = *(bf16x8*)(stb + e * 128 + (((8 * lg + 32 * kk) * 2) ^ ((e & 7) << 4)));
            }

        // per row-tile: QK^T (swapped) -> in-register S -> O = Q*S_state + S*V
#pragma unroll
        for (int ni2 = 0; ni2 < 2; ++ni2) {
            const int ni = ni2 ? (7 - w) : w;
            const int n = 16 * ni + lm;
            const int kmax = (ni >> 1) + 1;

            bf16x8 aq[2];
            {
                const float* qrow = q + (rowbase + n) * DD;
#pragma unroll
                for (int kk = 0; kk < 2; ++kk) {
                    const float4* p = (const float4*)(qrow + 8 * lg + 32 * kk);
                    float4 f0 = p[0], f1 = p[1];
                    bf16x8 u;
                    u[0] = (short)f2bf(f0.x); u[1] = (short)f2bf(f0.y);
                    u[2] = (short)f2bf(f0.z); u[3] = (short)f2bf(f0.w);
                    u[4] = (short)f2bf(f1.x); u[5] = (short)f2bf(f1.y);
                    u[6] = (short)f2bf(f1.z); u[7] = (short)f2bf(f1.w);
                    aq[kk] = u;
                }
            }

            unsigned a_s[4][4];
#pragma unroll
            for (int bb = 0; bb < 4; ++bb) {
                a_s[bb][0] = 0; a_s[bb][1] = 0; a_s[bb][2] = 0; a_s[bb][3] = 0;
            }

            float rsum = 0.f;
#pragma unroll
            for (int mi = 0; mi < 8; ++mi) {
                if (mi <= ni) {                       // wave-uniform
                    f32x4 cc = {0.f, 0.f, 0.f, 0.f};
                    const int mrow = 16 * mi + lm;
#pragma unroll
                    for (int kk = 0; kk < 2; ++kk) {
                        int byt = mrow * 128 + (((8 * lg + 32 * kk) * 2) ^ ((mrow & 7) << 4));
                        bf16x8 ak = *(bf16x8*)(kb + byt);
                        cc = __builtin_amdgcn_mfma_f32_16x16x32_bf16(ak, aq[kk], cc, 0, 0, 0);
                    }
                    const int m0 = 16 * mi + 4 * lg;
                    float v0 = (m0 + 0 <= n) ? cc[0] : 0.f;
                    float v1 = (m0 + 1 <= n) ? cc[1] : 0.f;
                    float v2 = (m0 + 2 <= n) ? cc[2] : 0.f;
                    float v3 = (m0 + 3 <= n) ? cc[3] : 0.f;
                    rsum += (v0 + v1) + (v2 + v3);
                    unsigned p_lo = (unsigned)f2bf(v0) | ((unsigned)f2bf(v1) << 16);
                    unsigned p_hi = (unsigned)f2bf(v2) | ((unsigned)f2bf(v3) << 16);
                    unsigned w0 = (unsigned)__shfl((int)p_lo, src1);
                    unsigned w1 = (unsigned)__shfl((int)p_hi, src1);
                    unsigned w2 = (unsigned)__shfl((int)p_lo, src2);
                    unsigned w3 = (unsigned)__shfl((int)p_hi, src2);
                    const bool take = (par == (mi & 1));
                    const int bb = mi >> 1;
                    a_s[bb][0] = take ? w0 : a_s[bb][0];
                    a_s[bb][1] = take ? w1 : a_s[bb][1];
                    a_s[bb][2] = take ? w2 : a_s[bb][2];
                    a_s[bb][3] = take ? w3 : a_s[bb][3];
                }
            }

            float qz = 0.f, qs = 0.f;
#pragma unroll
            for (int kk = 0; kk < 2; ++kk) {
#pragma unroll
                for (int i = 0; i < 8; ++i) {
                    float qf = bf2f((unsigned short)aq[kk][i]);
                    qz += qf * zi_lds[8 * lg + 32 * kk + i];
                    qs += qf;
                }
            }
            float part = rsum + qz + EPSV * qs;
            part += __shfl_xor(part, 16);
            part += __shfl_xor(part, 32);
            const float dinv = 1.f / part;

            f32x4 acc3[4];
#pragma unroll
            for (int ei = 0; ei < 4; ++ei) {
                f32x4 cc = {0.f, 0.f, 0.f, 0.f};
                const int e = 16 * ei + lm;
                cc = __builtin_amdgcn_mfma_f32_16x16x32_bf16(aq[0], b_st[ei][0], cc, 0, 0, 0);
                cc = __builtin_amdgcn_mfma_f32_16x16x32_bf16(aq[1], b_st[ei][1], cc, 0, 0, 0);
#pragma unroll
                for (int kk = 0; kk < 4; ++kk) {
                    if (kk < kmax) {                  // wave-uniform
                        union { unsigned u[4]; bf16x8 f; } as;
                        as.u[0] = a_s[kk][0]; as.u[1] = a_s[kk][1];
                        as.u[2] = a_s[kk][2]; as.u[3] = a_s[kk][3];
                        int bytB = (lg + 4 * kk) * 1024 + e * 16;
                        bf16x8 bv = *(bf16x8*)(vb + bytB);
                        cc = __builtin_amdgcn_mfma_f32_16x16x32_bf16(as.f, bv, cc, 0, 0, 0);
                    }
                }
                acc3[ei] = cc;
            }

#pragma unroll
            for (int r = 0; r < 4; ++r) {
                float dr = __shfl(dinv, 4 * lg + r);
                const int nr = 16 * ni + 4 * lg + r;
                float* orow = out + (rowbase + nr) * EE + lm;
#pragma unroll
                for (int ei = 0; ei < 4; ++ei)
                    orow[16 * ei] = acc3[ei][r] * dr;
            }
        }
    }
}

extern "C" void kernel_launch(void* const* d_in, const int* in_sizes, int n_in,
                              void* d_out, int out_size, void* d_ws, size_t ws_size,
                              hipStream_t stream)
{
    (void)in_sizes; (void)n_in; (void)out_size; (void)ws_size;
    const float* q = (const float*)d_in[0];
    const float* k = (const float*)d_in[1];
    const float* v = (const float*)d_in[2];
    float* out = (float*)d_out;
    unsigned short* kvT = (unsigned short*)d_ws;      // 8 MB bf16 per-chunk states
    float* ks = (float*)(kvT + KV_ELEMS);             // +256 KB fp32 per-chunk k-sums
    int* cnt = (int*)(ks + NBH * NC * DD);            // +128 B per-bh arrival counters

    hipMemsetAsync(cnt, 0, NBH * sizeof(int), stream);
    la_fused<<<512, 256, 0, stream>>>(q, k, v, kvT, ks, cnt, out);
}

// Round 14
// 48.723 us; speedup vs baseline: 2.5510x; 2.5510x over previous
//
#include <hip/hip_runtime.h>

// Linear attention (chunked cumulative state), B=4 H=8 N=4096 D=E=64 CHUNK=128.
// phase1: per-chunk K^T V via bf16 MFMA + fp32 k-colsums (column-pack staging).
// phase2: register prefix scan over chunks (fp32 accum, bf16 prefixes, fp32 tails).
// phase3: per-chunk output via bf16 MFMA. Swapped QK^T; S kept ENTIRELY in
//         registers (intra-wave shfl redistribution, no s_lds, 1 barrier total);
//         LDS 33KB -> 4 blocks/CU; state B-frags direct from global.
// (Round-11 state, re-confirmed best: 48.8 us. Fusion attempts r7/r13 regressed.)

#define CHUNKSZ 128
#define DD 64
#define EE 64
#define NC 32          // N / CHUNK
#define NBH 32         // B*H
#define NSEQ 4096
#define EPSV 1e-6f
#define OUT0 (NBH * NSEQ * EE)           // start of Z output
#define KV_ELEMS (NBH * NC * DD * EE)    // ushort count

typedef short bf16x8 __attribute__((ext_vector_type(8)));
typedef short bf16x4 __attribute__((ext_vector_type(4)));
typedef float f32x4  __attribute__((ext_vector_type(4)));

__device__ __forceinline__ unsigned short f2bf(float f) {
    union { float f; unsigned u; } x; x.f = f;
    unsigned u = x.u + 0x7FFFu + ((x.u >> 16) & 1u);   // RNE
    return (unsigned short)(u >> 16);
}
__device__ __forceinline__ float bf2f(unsigned short s) {
    union { unsigned u; float f; } x; x.u = ((unsigned)s) << 16;
    return x.f;
}

// ---------------- phase 1: kvT[e][d] = sum_m K[m][d] V[m][e]  (bf16) ----------------
__global__ __launch_bounds__(256) void la_phase1(
    const float* __restrict__ k, const float* __restrict__ v,
    unsigned short* __restrict__ kvT, float* __restrict__ ks)
{
    const int blk = blockIdx.x;
    const int bh = blk / NC, c = blk % NC;
    const size_t rowbase = (size_t)bh * NSEQ + (size_t)c * CHUNKSZ;

    __shared__ alignas(16) unsigned short kT[CHUNKSZ * DD];
    __shared__ alignas(16) unsigned short vT[CHUNKSZ * EE];
    __shared__ float ksp[4][DD];

    char* kb = (char*)kT;
    char* vb = (char*)vT;

    const int t = threadIdx.x;
    const int w = t >> 6, l = t & 63;
    const int lg = l >> 4, lm = l & 15;
    const int col = t & 63;

    float kpart = 0.f;
#pragma unroll
    for (int pass = 0; pass < 4; ++pass) {
        const int mg = w + 4 * pass;
        const float* kp = k + (rowbase + mg * 8) * DD + col;
        const float* vp = v + (rowbase + mg * 8) * EE + col;
        float kf[8], vf[8];
#pragma unroll
        for (int j = 0; j < 8; ++j) kf[j] = kp[(size_t)j * DD];
#pragma unroll
        for (int j = 0; j < 8; ++j) vf[j] = vp[(size_t)j * EE];
        bf16x8 ku, vu;
#pragma unroll
        for (int j = 0; j < 8; ++j) {
            kpart += kf[j];
            ku[j] = (short)f2bf(kf[j]);
            vu[j] = (short)f2bf(vf[j]);
        }
        *(bf16x8*)(kb + mg * 1024 + col * 16) = ku;
        *(bf16x8*)(vb + mg * 1024 + col * 16) = vu;
    }
    ksp[w][col] = kpart;
    __syncthreads();

    f32x4 acc[4] = {};
#pragma unroll
    for (int kk = 0; kk < 4; ++kk) {
        bf16x8 aK = *(bf16x8*)(kb + (lg + 4 * kk) * 1024 + (16 * w + lm) * 16);
#pragma unroll
        for (int ei = 0; ei < 4; ++ei) {
            bf16x8 bV = *(bf16x8*)(vb + (lg + 4 * kk) * 1024 + (16 * ei + lm) * 16);
            acc[ei] = __builtin_amdgcn_mfma_f32_16x16x32_bf16(aK, bV, acc[ei], 0, 0, 0);
        }
    }
    unsigned short* kvout = kvT + (size_t)(bh * NC + c) * DD * EE;
#pragma unroll
    for (int ei = 0; ei < 4; ++ei) {
        bf16x4 u;
        u[0] = (short)f2bf(acc[ei][0]); u[1] = (short)f2bf(acc[ei][1]);
        u[2] = (short)f2bf(acc[ei][2]); u[3] = (short)f2bf(acc[ei][3]);
        *(bf16x4*)(kvout + (16 * ei + lm) * DD + 16 * w + 4 * lg) = u;
    }
    if (t < DD)
        ks[(size_t)(bh * NC + c) * DD + t] = ksp[0][t] + ksp[1][t] + ksp[2][t] + ksp[3][t];
}

// ---------------- phase 2: exclusive prefix scan over chunks ----------------
__global__ __launch_bounds__(64) void la_phase2(
    unsigned short* __restrict__ kvT, float* __restrict__ ks, float* __restrict__ out)
{
    const int bid = blockIdx.x, t = threadIdx.x;
    if (bid < 256) {
        const int gid = bid * 64 + t;            // 0..16383
        const int bh = gid >> 9;
        const int g = gid & 511;                 // group of 8 ushorts in [e][d] tile
        unsigned short* base = kvT + (size_t)bh * (NC * DD * EE) + (size_t)g * 8;
        bf16x8 vals[NC];
#pragma unroll
        for (int c = 0; c < NC; ++c)
            vals[c] = *(const bf16x8*)(base + (size_t)c * (DD * EE));
        float run[8] = {};
#pragma unroll
        for (int c = 0; c < NC; ++c) {
            bf16x8 pr;
#pragma unroll
            for (int j = 0; j < 8; ++j) pr[j] = (short)f2bf(run[j]);
            *(bf16x8*)(base + (size_t)c * (DD * EE)) = pr;
#pragma unroll
            for (int j = 0; j < 8; ++j) run[j] += bf2f((unsigned short)vals[c][j]);
        }
        const int e = g >> 3, d0 = (g & 7) * 8;
        float* Sout = out + OUT0 + NBH * DD + (size_t)bh * DD * EE;
#pragma unroll
        for (int j = 0; j < 8; ++j)
            Sout[(size_t)(d0 + j) * EE + e] = run[j];
    } else {
        const int tid = (bid - 256) * 64 + t;    // 0..2047 = bh*64 + d
        const int bh = tid >> 6, d = tid & 63;
        float vals[NC];
#pragma unroll
        for (int c = 0; c < NC; ++c)
            vals[c] = ks[(size_t)(bh * NC + c) * DD + d];
        float run = 0.f;
#pragma unroll
        for (int c = 0; c < NC; ++c) {
            float x = vals[c];
            ks[(size_t)(bh * NC + c) * DD + d] = run;
            run += x;
        }
        out[OUT0 + tid] = run;                   // Z tail
    }
}

// ---------------- phase 3: per-chunk output, S fully in registers ----------------
// k_lds row-major [m][d] swizzled: byte(m,d) = m*128 + ((d*2) ^ ((m&7)<<4))
// v_lds subtiled:  byte(m,e) = (m>>3)*1024 + e*16 + (m&7)*2
// wave w owns row-tiles ni = w and ni = 7-w (balanced causal work).
// S redistribution: source lane (lg_s,lm) holds S[16mi+4lg_s+r][16ni+lm]; target
// A-frag word j of block kk comes from tile mi=2kk+(lg>>1), src lane 2(lg&1)+(j>>1),
// lo/hi pair = j&1. 4 shfls per tile, select by parity.
__global__ __launch_bounds__(256) void la_phase3(
    const float* __restrict__ q, const float* __restrict__ k,
    const float* __restrict__ v, const unsigned short* __restrict__ kvT,
    const float* __restrict__ ks, float* __restrict__ out)
{
    const int blk = blockIdx.x;
    const int bh = blk / NC, c = blk % NC;
    const size_t rowbase = (size_t)bh * NSEQ + (size_t)c * CHUNKSZ;

    __shared__ alignas(16) unsigned short k_lds[CHUNKSZ * DD];   // 16 KB
    __shared__ alignas(16) unsigned short v_lds[CHUNKSZ * EE];   // 16 KB
    __shared__ float zi_lds[DD];

    char* kb = (char*)k_lds;
    char* vb = (char*)v_lds;

    const int t  = threadIdx.x;
    const int w  = t >> 6;
    const int l  = t & 63;
    const int lg = l >> 4;
    const int lm = l & 15;

    // ---- staging ----
    {
        const float4* kg = (const float4*)(k + rowbase * DD);
#pragma unroll
        for (int i = 0; i < 8; ++i) {
            int idx = t + i * 256;
            int m = idx >> 4, c4 = idx & 15;
            float4 f = kg[idx];
            bf16x4 u;
            u[0] = (short)f2bf(f.x); u[1] = (short)f2bf(f.y);
            u[2] = (short)f2bf(f.z); u[3] = (short)f2bf(f.w);
            int byt = m * 128 + ((c4 * 8) ^ ((m & 7) << 4));
            *(bf16x4*)(kb + byt) = u;
        }
    }
    {
        const int col = t & 63;
#pragma unroll
        for (int pass = 0; pass < 4; ++pass) {
            const int mg = (t >> 6) + 4 * pass;
            const float* vp = v + (rowbase + mg * 8) * EE + col;
            float vf[8];
#pragma unroll
            for (int j = 0; j < 8; ++j) vf[j] = vp[(size_t)j * EE];
            bf16x8 u;
#pragma unroll
            for (int j = 0; j < 8; ++j) u[j] = (short)f2bf(vf[j]);
            *(bf16x8*)(vb + mg * 1024 + col * 16) = u;
        }
    }
    // state B-frags direct from global ([e][d] row-major, L2/L3-warm)
    const unsigned short* stc = kvT + (size_t)(bh * NC + c) * DD * EE;
    bf16x8 b_st[4][2];
#pragma unroll
    for (int ei = 0; ei < 4; ++ei)
#pragma unroll
        for (int kk = 0; kk < 2; ++kk)
            b_st[ei][kk] = *(const bf16x8*)(stc + (size_t)(16 * ei + lm) * DD + 8 * lg + 32 * kk);

    // Z exclusive prefix for this chunk
    if (t < DD) zi_lds[t] = ks[(size_t)(bh * NC + c) * DD + t];
    __syncthreads();      // the ONLY barrier

    const int src1 = 32 * (lg & 1) + lm;
    const int src2 = src1 + 16;
    const int par  = lg >> 1;

#pragma unroll
    for (int ni2 = 0; ni2 < 2; ++ni2) {
        const int ni = ni2 ? (7 - w) : w;
        const int n = 16 * ni + lm;
        const int kmax = (ni >> 1) + 1;

        // Q A-frags for this ni
        bf16x8 aq[2];
        {
            const float* qrow = q + (rowbase + n) * DD;
#pragma unroll
            for (int kk = 0; kk < 2; ++kk) {
                const float4* p = (const float4*)(qrow + 8 * lg + 32 * kk);
                float4 f0 = p[0], f1 = p[1];
                bf16x8 u;
                u[0] = (short)f2bf(f0.x); u[1] = (short)f2bf(f0.y);
                u[2] = (short)f2bf(f0.z); u[3] = (short)f2bf(f0.w);
                u[4] = (short)f2bf(f1.x); u[5] = (short)f2bf(f1.y);
                u[6] = (short)f2bf(f1.z); u[7] = (short)f2bf(f1.w);
                aq[kk] = u;
            }
        }

        // S A-frag words (zero-init covers the ragged causal edge)
        unsigned a_s[4][4];
#pragma unroll
        for (int b = 0; b < 4; ++b) {
            a_s[b][0] = 0; a_s[b][1] = 0; a_s[b][2] = 0; a_s[b][3] = 0;
        }

        // swapped QK^T tiles -> mask -> pack -> intra-wave redistribute
        float rsum = 0.f;
#pragma unroll
        for (int mi = 0; mi < 8; ++mi) {
            if (mi <= ni) {                       // wave-uniform
                f32x4 cc = {0.f, 0.f, 0.f, 0.f};
                const int mrow = 16 * mi + lm;
#pragma unroll
                for (int kk = 0; kk < 2; ++kk) {
                    int byt = mrow * 128 + (((8 * lg + 32 * kk) * 2) ^ ((mrow & 7) << 4));
                    bf16x8 ak = *(bf16x8*)(kb + byt);
                    cc = __builtin_amdgcn_mfma_f32_16x16x32_bf16(ak, aq[kk], cc, 0, 0, 0);
                }
                const int m0 = 16 * mi + 4 * lg;
                float v0 = (m0 + 0 <= n) ? cc[0] : 0.f;
                float v1 = (m0 + 1 <= n) ? cc[1] : 0.f;
                float v2 = (m0 + 2 <= n) ? cc[2] : 0.f;
                float v3 = (m0 + 3 <= n) ? cc[3] : 0.f;
                rsum += (v0 + v1) + (v2 + v3);
                unsigned p_lo = (unsigned)f2bf(v0) | ((unsigned)f2bf(v1) << 16);
                unsigned p_hi = (unsigned)f2bf(v2) | ((unsigned)f2bf(v3) << 16);
                unsigned w0 = (unsigned)__shfl((int)p_lo, src1);
                unsigned w1 = (unsigned)__shfl((int)p_hi, src1);
                unsigned w2 = (unsigned)__shfl((int)p_lo, src2);
                unsigned w3 = (unsigned)__shfl((int)p_hi, src2);
                const bool take = (par == (mi & 1));
                const int b = mi >> 1;
                a_s[b][0] = take ? w0 : a_s[b][0];
                a_s[b][1] = take ? w1 : a_s[b][1];
                a_s[b][2] = take ? w2 : a_s[b][2];
                a_s[b][3] = take ? w3 : a_s[b][3];
            }
        }

        // denominator: rsum + q.Z + eps*sum(q), reduced across the 4 lg lanes
        float qz = 0.f, qs = 0.f;
#pragma unroll
        for (int kk = 0; kk < 2; ++kk) {
#pragma unroll
            for (int i = 0; i < 8; ++i) {
                float qf = bf2f((unsigned short)aq[kk][i]);
                qz += qf * zi_lds[8 * lg + 32 * kk + i];
                qs += qf;
            }
        }
        float part = rsum + qz + EPSV * qs;
        part += __shfl_xor(part, 16);
        part += __shfl_xor(part, 32);
        const float dinv = 1.f / part;            // every lane: row 16ni+lm

        // O = Q x S_state + S x V
        f32x4 acc[4];
#pragma unroll
        for (int ei = 0; ei < 4; ++ei) {
            f32x4 cc = {0.f, 0.f, 0.f, 0.f};
            const int e = 16 * ei + lm;
            cc = __builtin_amdgcn_mfma_f32_16x16x32_bf16(aq[0], b_st[ei][0], cc, 0, 0, 0);
            cc = __builtin_amdgcn_mfma_f32_16x16x32_bf16(aq[1], b_st[ei][1], cc, 0, 0, 0);
#pragma unroll
            for (int kk = 0; kk < 4; ++kk) {
                if (kk < kmax) {                  // wave-uniform
                    union { unsigned u[4]; bf16x8 f; } as;
                    as.u[0] = a_s[kk][0]; as.u[1] = a_s[kk][1];
                    as.u[2] = a_s[kk][2]; as.u[3] = a_s[kk][3];
                    int bytB = (lg + 4 * kk) * 1024 + e * 16;
                    bf16x8 bv = *(bf16x8*)(vb + bytB);
                    cc = __builtin_amdgcn_mfma_f32_16x16x32_bf16(as.f, bv, cc, 0, 0, 0);
                }
            }
            acc[ei] = cc;
        }

        // epilogue: dinv for row 16ni+4lg+r lives at lane (lg=0, lm=4lg+r)
#pragma unroll
        for (int r = 0; r < 4; ++r) {
            float dr = __shfl(dinv, 4 * lg + r);
            const int nr = 16 * ni + 4 * lg + r;
            float* orow = out + (rowbase + nr) * EE + lm;
#pragma unroll
            for (int ei = 0; ei < 4; ++ei)
                orow[16 * ei] = acc[ei][r] * dr;
        }
    }
}

extern "C" void kernel_launch(void* const* d_in, const int* in_sizes, int n_in,
                              void* d_out, int out_size, void* d_ws, size_t ws_size,
                              hipStream_t stream)
{
    (void)in_sizes; (void)n_in; (void)out_size; (void)ws_size;
    const float* q = (const float*)d_in[0];
    const float* k = (const float*)d_in[1];
    const float* v = (const float*)d_in[2];
    float* out = (float*)d_out;
    unsigned short* kvT = (unsigned short*)d_ws;      // 8 MB bf16 per-chunk states
    float* ks = (float*)(kvT + KV_ELEMS);             // +256 KB fp32 per-chunk k-sums

    la_phase1<<<NBH * NC, 256, 0, stream>>>(k, v, kvT, ks);
    la_phase2<<<288, 64, 0, stream>>>(kvT, ks, out);
    la_phase3<<<NBH * NC, 256, 0, stream>>>(q, k, v, kvT, ks, out);
}